// Round 3
// baseline (13146.088 us; speedup 1.0000x reference)
//
#include <hip/hip_runtime.h>

// Problem dims
#define S_ 256
#define B_ 32
#define I_ 256
#define H_ 512
#define H3_ 1536
#define O_ 256
#define G_ 16          // M*P
#define SB_ 8192       // S*B
#define SBO_ 2097152   // S*B*O
#define NSL 32         // col-slices per group (16 cols each)
#define SPIN_CAP (1u << 20)

typedef __attribute__((ext_vector_type(8))) short bf16x8;
typedef __attribute__((ext_vector_type(4))) float f32x4;

#define MFMA16(a, b, c) __builtin_amdgcn_mfma_f32_16x16x32_bf16((a), (b), (c), 0, 0, 0)

static __device__ __forceinline__ unsigned short f2bf(float f) {
  union { float f; unsigned u; } x; x.f = f;
  unsigned u = x.u + 0x7fffu + ((x.u >> 16) & 1u);   // RNE, finite inputs
  return (unsigned short)(u >> 16);
}
static __device__ __forceinline__ float sigmoidf_(float x) {
  return 1.f / (1.f + __expf(-x));
}

// ---------------- f32 -> bf16 convert ----------------
__global__ void k_cvt(const float* __restrict__ src, unsigned short* __restrict__ dst, int n) {
  int i = blockIdx.x * blockDim.x + threadIdx.x;
  int st = gridDim.x * blockDim.x;
  for (; i < n; i += st) dst[i] = f2bf(src[i]);
}

// Swizzled LDS read of a bf16x8 B-fragment; row size = 1<<shift bytes.
static __device__ __forceinline__ bf16x8 lds_b(const char* lds, int lr, int kk, int shift) {
  return *(const bf16x8*)(lds + (((lr << shift) + kk * 2) ^ ((lr & 7) << 4)));
}

// Per-group device barrier: monotonic counter, release-add / relaxed-spin /
// agent acquire fence (same structure as ROCm's CG grid barrier).
static __device__ __forceinline__ void gbar(unsigned* cnt, unsigned target) {
  __syncthreads();                       // all waves' stores issued & drained
  if (threadIdx.x == 0) {
    __hip_atomic_fetch_add(cnt, 1u, __ATOMIC_RELEASE, __HIP_MEMORY_SCOPE_AGENT);
    unsigned it = 0;
    while (__hip_atomic_load(cnt, __ATOMIC_RELAXED, __HIP_MEMORY_SCOPE_AGENT) < target) {
      __builtin_amdgcn_s_sleep(2);
      if (++it > SPIN_CAP) break;        // degrade to wrong-numbers, never hang
    }
  }
  __syncthreads();
  __builtin_amdgcn_fence(__ATOMIC_ACQUIRE, "agent");
}

// blockIdx -> (group, slice) so a group's 32 blocks share an XCD under the
// "XCD = blockIdx % 8" dispatch heuristic (perf-only; correctness is agent-scope).
#define GRP_OF(blk) ((((blk) & 7) << 1) | ((blk) >> 8))
#define CSL_OF(blk) (((blk) >> 3) & 31)

// ---------------- layer 0: persistent recurrence, fused x@w_ih0^T ----------------
// 512 blocks x 128 thr (2 waves). Block = (group, 16-col slice). LDS 72KB -> 2 blk/CU.
__global__ __launch_bounds__(128) void k_gru0(
    const float* __restrict__ hidden,
    const unsigned short* __restrict__ xb,
    const unsigned short* __restrict__ wih0b,
    const unsigned short* __restrict__ whh0b,
    const float* __restrict__ b_ih0,
    const float* __restrict__ b_hh0,
    const float* __restrict__ mask,
    unsigned short* __restrict__ y0m,
    unsigned short* __restrict__ hbuf,
    float* __restrict__ hid_out,
    unsigned* __restrict__ bar) {
  __shared__ char lds[73728];            // whh slice 48KB @0, wih slice 24KB @49152
  const int blk = blockIdx.x;
  const int grp = GRP_OF(blk), csl = CSL_OF(blk);
  const int colBase = csl * 16;
  const int m = grp >> 2;
  const int tid = threadIdx.x;
  const int w = tid >> 6, l = tid & 63;
  const int la = l & 15, lb = l >> 4;

  // stage whh0 slice: 48 rows (gate*16 + c) x 512 bf16, 1KB rows, XOR-swizzled
  for (int idx = tid; idx < 48 * 64; idx += 128) {
    int lr = idx >> 6, kc = (idx & 63) << 3;
    int gt = lr >> 4, c = lr & 15;
    bf16x8 v = *(const bf16x8*)(whh0b + ((size_t)m * H3_ + gt * H_ + colBase + c) * H_ + kc);
    *(bf16x8*)(lds + ((lr * 1024 + kc * 2) ^ ((lr & 7) << 4))) = v;
  }
  // stage wih0 slice: 48 rows x 256 bf16, 512B rows, XOR-swizzled
  char* ldsi = lds + 49152;
  for (int idx = tid; idx < 48 * 32; idx += 128) {
    int lr = idx >> 5, kc = (idx & 31) << 3;
    int gt = lr >> 4, c = lr & 15;
    bf16x8 v = *(const bf16x8*)(wih0b + ((size_t)m * H3_ + gt * H_ + colBase + c) * I_ + kc);
    *(bf16x8*)(ldsi + ((lr * 512 + kc * 2) ^ ((lr & 7) << 4))) = v;
  }

  const int jh = colBase + la;           // this lane's h column
  const int b0 = w * 16 + lb * 4;        // first of 4 batch rows (D-frag rows)
  float hown[4];
#pragma unroll
  for (int r = 0; r < 4; ++r) {
    float h0 = hidden[((size_t)(grp * 2 + 0) * B_ + b0 + r) * H_ + jh];
    hown[r] = h0;
    hbuf[((size_t)(grp * 2 + 0) * B_ + b0 + r) * H_ + jh] = f2bf(h0);
  }
  const float bir = b_ih0[m * H3_ + jh];
  const float biz = b_ih0[m * H3_ + H_ + jh];
  const float bin = b_ih0[m * H3_ + 2 * H_ + jh];
  const float bhr = b_hh0[m * H3_ + jh];
  const float bhz = b_hh0[m * H3_ + H_ + jh];
  const float bhn = b_hh0[m * H3_ + 2 * H_ + jh];
  const int lrr = la, lrz = 16 + la, lrn = 32 + la;

  unsigned* cnt = bar + grp * 64;
  gbar(cnt, NSL);                        // h0 visible group-wide

  for (int s = 0; s < S_; ++s) {
    const int rb = s & 1;
    const unsigned short* hsrc = hbuf + (size_t)(grp * 2 + rb) * B_ * H_;
    unsigned short* hdst = hbuf + (size_t)(grp * 2 + (rb ^ 1)) * B_ * H_;
    const unsigned short* xrow = xb + ((size_t)s * B_ + w * 16 + la) * I_;
    const unsigned short* hrow = hsrc + (size_t)(w * 16 + la) * H_;
    f32x4 iR = {}, iZ = {}, iN = {}, hR = {}, hZ = {}, hN = {};
#pragma unroll
    for (int kt = 0; kt < 8; ++kt) {     // K=256 ih chains
      int kk = kt * 32 + lb * 8;
      bf16x8 ax = *(const bf16x8*)(xrow + kk);
      iR = MFMA16(ax, lds_b(ldsi, lrr, kk, 9), iR);
      iZ = MFMA16(ax, lds_b(ldsi, lrz, kk, 9), iZ);
      iN = MFMA16(ax, lds_b(ldsi, lrn, kk, 9), iN);
    }
#pragma unroll
    for (int kt = 0; kt < 16; ++kt) {    // K=512 hh chains
      int kk = kt * 32 + lb * 8;
      bf16x8 ah = *(const bf16x8*)(hrow + kk);
      hR = MFMA16(ah, lds_b(lds, lrr, kk, 10), hR);
      hZ = MFMA16(ah, lds_b(lds, lrz, kk, 10), hZ);
      hN = MFMA16(ah, lds_b(lds, lrn, kk, 10), hN);
    }
#pragma unroll
    for (int r = 0; r < 4; ++r) {
      int b = b0 + r;
      float rr = sigmoidf_(iR[r] + bir + hR[r] + bhr);
      float zz = sigmoidf_(iZ[r] + biz + hZ[r] + bhz);
      float nn = tanhf(iN[r] + bin + rr * (hN[r] + bhn));
      float hn = (1.f - zz) * nn + zz * hown[r];
      hown[r] = hn;
      hdst[(size_t)b * H_ + jh] = f2bf(hn);
      size_t mi = (((size_t)grp * S_ + s) * B_ + b) * H_ + jh;
      y0m[mi] = f2bf(hn * mask[mi]);
    }
    if (s + 1 < S_) gbar(cnt, (unsigned)NSL * (s + 2));
  }
#pragma unroll
  for (int r = 0; r < 4; ++r)
    hid_out[((size_t)(grp * 2 + 0) * B_ + b0 + r) * H_ + jh] = hown[r];
}

// ---------------- layer 1: persistent recurrence, fused y0@w_ih1^T ----------------
// w_ih1 B-frags stream from L1/L2 (same 48KB slice every step). LDS 48KB.
__global__ __launch_bounds__(128) void k_gru1(
    const float* __restrict__ hidden,
    const unsigned short* __restrict__ y0m,
    const unsigned short* __restrict__ wih1b,
    const unsigned short* __restrict__ whh1b,
    const float* __restrict__ b_ih1,
    const float* __restrict__ b_hh1,
    unsigned short* __restrict__ y1l,
    unsigned short* __restrict__ hbuf,
    float* __restrict__ hid_out,
    unsigned* __restrict__ bar) {
  __shared__ char lds[49152];
  const int blk = blockIdx.x;
  const int grp = GRP_OF(blk), csl = CSL_OF(blk);
  const int colBase = csl * 16;
  const int m = grp >> 2;
  const int tid = threadIdx.x;
  const int w = tid >> 6, l = tid & 63;
  const int la = l & 15, lb = l >> 4;

  for (int idx = tid; idx < 48 * 64; idx += 128) {
    int lr = idx >> 6, kc = (idx & 63) << 3;
    int gt = lr >> 4, c = lr & 15;
    bf16x8 v = *(const bf16x8*)(whh1b + ((size_t)m * H3_ + gt * H_ + colBase + c) * H_ + kc);
    *(bf16x8*)(lds + ((lr * 1024 + kc * 2) ^ ((lr & 7) << 4))) = v;
  }

  const int jh = colBase + la;
  const int b0 = w * 16 + lb * 4;
  float hown[4];
#pragma unroll
  for (int r = 0; r < 4; ++r) {
    float h0 = hidden[((size_t)(grp * 2 + 1) * B_ + b0 + r) * H_ + jh];
    hown[r] = h0;
    hbuf[((size_t)(grp * 2 + 0) * B_ + b0 + r) * H_ + jh] = f2bf(h0);
  }
  const float bir = b_ih1[m * H3_ + jh];
  const float biz = b_ih1[m * H3_ + H_ + jh];
  const float bin = b_ih1[m * H3_ + 2 * H_ + jh];
  const float bhr = b_hh1[m * H3_ + jh];
  const float bhz = b_hh1[m * H3_ + H_ + jh];
  const float bhn = b_hh1[m * H3_ + 2 * H_ + jh];
  const unsigned short* wr = wih1b + ((size_t)m * H3_ + jh) * H_;
  const unsigned short* wz = wih1b + ((size_t)m * H3_ + H_ + jh) * H_;
  const unsigned short* wn = wih1b + ((size_t)m * H3_ + 2 * H_ + jh) * H_;
  const int lrr = la, lrz = 16 + la, lrn = 32 + la;

  unsigned* cnt = bar + grp * 64;
  gbar(cnt, NSL);

  for (int s = 0; s < S_; ++s) {
    const int rb = s & 1;
    const unsigned short* hsrc = hbuf + (size_t)(grp * 2 + rb) * B_ * H_;
    unsigned short* hdst = hbuf + (size_t)(grp * 2 + (rb ^ 1)) * B_ * H_;
    const unsigned short* yrow = y0m + (((size_t)grp * S_ + s) * B_ + w * 16 + la) * H_;
    const unsigned short* hrow = hsrc + (size_t)(w * 16 + la) * H_;
    f32x4 iR = {}, iZ = {}, iN = {}, hR = {}, hZ = {}, hN = {};
#pragma unroll
    for (int kt = 0; kt < 16; ++kt) {
      int kk = kt * 32 + lb * 8;
      bf16x8 ay = *(const bf16x8*)(yrow + kk);
      iR = MFMA16(ay, *(const bf16x8*)(wr + kk), iR);
      iZ = MFMA16(ay, *(const bf16x8*)(wz + kk), iZ);
      iN = MFMA16(ay, *(const bf16x8*)(wn + kk), iN);
      bf16x8 ah = *(const bf16x8*)(hrow + kk);
      hR = MFMA16(ah, lds_b(lds, lrr, kk, 10), hR);
      hZ = MFMA16(ah, lds_b(lds, lrz, kk, 10), hZ);
      hN = MFMA16(ah, lds_b(lds, lrn, kk, 10), hN);
    }
#pragma unroll
    for (int r = 0; r < 4; ++r) {
      int b = b0 + r;
      float rr = sigmoidf_(iR[r] + bir + hR[r] + bhr);
      float zz = sigmoidf_(iZ[r] + biz + hZ[r] + bhz);
      float nn = tanhf(iN[r] + bin + rr * (hN[r] + bhn));
      float hn = (1.f - zz) * nn + zz * hown[r];
      hown[r] = hn;
      hdst[(size_t)b * H_ + jh] = f2bf(hn);
      float a = hn >= 0.f ? hn : 0.01f * hn;         // LeakyReLU pre-store
      y1l[(((size_t)grp * S_ + s) * B_ + b) * H_ + jh] = f2bf(a);
    }
    if (s + 1 < S_) gbar(cnt, (unsigned)NSL * (s + 2));
  }
#pragma unroll
  for (int r = 0; r < 4; ++r)
    hid_out[((size_t)(grp * 2 + 1) * B_ + b0 + r) * H_ + jh] = hown[r];
}

// ---------------- preds = lrelu(y1) @ lin_w^T + lin_b ----------------
// grid: G * (SB/64) * (O/64) = 16*128*4 = 8192 blocks, 256 thr, 64x64 tiles
__global__ __launch_bounds__(256) void k_preds(const unsigned short* __restrict__ y1l,
                                               const unsigned short* __restrict__ linwb,
                                               const float* __restrict__ lin_b,
                                               float* __restrict__ preds) {
  int bid = blockIdx.x;
  int grp = bid >> 9;
  int rm = bid & 511;
  int rt = rm >> 2, ct = rm & 3;
  int m = grp >> 2;
  int w = threadIdx.x >> 6, l = threadIdx.x & 63;
  int la = l & 15, lb = l >> 4;
  int rowBase = rt * 64 + (w & 1) * 32;
  int colBase = ct * 64 + (w >> 1) * 32;
  f32x4 acc[2][2] = {};
  for (int kt = 0; kt < 16; ++kt) {
    int k = kt * 32 + lb * 8;
    bf16x8 a0 = *(const bf16x8*)(y1l + ((size_t)grp * SB_ + rowBase + la) * H_ + k);
    bf16x8 a1 = *(const bf16x8*)(y1l + ((size_t)grp * SB_ + rowBase + 16 + la) * H_ + k);
    bf16x8 bb0 = *(const bf16x8*)(linwb + ((size_t)m * O_ + colBase + la) * H_ + k);
    bf16x8 bb1 = *(const bf16x8*)(linwb + ((size_t)m * O_ + colBase + 16 + la) * H_ + k);
    acc[0][0] = MFMA16(a0, bb0, acc[0][0]);
    acc[0][1] = MFMA16(a0, bb1, acc[0][1]);
    acc[1][0] = MFMA16(a1, bb0, acc[1][0]);
    acc[1][1] = MFMA16(a1, bb1, acc[1][1]);
  }
  for (int fr = 0; fr < 2; ++fr)
    for (int fc = 0; fc < 2; ++fc)
#pragma unroll
      for (int r = 0; r < 4; ++r) {
        int row = rowBase + fr * 16 + lb * 4 + r;
        int col = colBase + fc * 16 + la;
        preds[((size_t)grp * SB_ + row) * O_ + col] = acc[fr][fc][r] + lin_b[m * O_ + col];
      }
}

// ---------------- mean / unbiased var over the 16 samples ----------------
__global__ __launch_bounds__(256) void k_meanvar(const float* __restrict__ preds,
                                                 float* __restrict__ om,
                                                 float* __restrict__ ov, int n) {
  int i = blockIdx.x * 256 + threadIdx.x;
  if (i >= n) return;
  float v[16], sum = 0.f;
#pragma unroll
  for (int g = 0; g < 16; ++g) { v[g] = preds[(size_t)g * n + i]; sum += v[g]; }
  float mu = sum * 0.0625f;
  float s2 = 0.f;
#pragma unroll
  for (int g = 0; g < 16; ++g) { float d = v[g] - mu; s2 += d * d; }
  om[i] = mu;
  ov[i] = s2 * (1.f / 15.f);
}

extern "C" void kernel_launch(void* const* d_in, const int* in_sizes, int n_in,
                              void* d_out, int out_size, void* d_ws, size_t ws_size,
                              hipStream_t stream) {
  const float* input  = (const float*)d_in[0];
  const float* hidden = (const float*)d_in[1];
  const float* w_ih0  = (const float*)d_in[2];
  const float* w_hh0  = (const float*)d_in[3];
  const float* b_ih0  = (const float*)d_in[4];
  const float* b_hh0  = (const float*)d_in[5];
  const float* w_ih1  = (const float*)d_in[6];
  const float* w_hh1  = (const float*)d_in[7];
  const float* b_ih1  = (const float*)d_in[8];
  const float* b_hh1  = (const float*)d_in[9];
  const float* lin_w  = (const float*)d_in[10];
  const float* lin_b  = (const float*)d_in[11];
  const float* mask   = (const float*)d_in[12];

  // ws layout (bytes), total 297,811,968 (~284 MB)
  char* ws = (char*)d_ws;
  unsigned short* xb    = (unsigned short*)(ws + 0);           //  4,194,304
  unsigned short* wih0b = (unsigned short*)(ws + 4194304);     //  3,145,728
  unsigned short* whh0b = (unsigned short*)(ws + 7340032);     //  6,291,456
  unsigned short* wih1b = (unsigned short*)(ws + 13631488);    //  6,291,456
  unsigned short* whh1b = (unsigned short*)(ws + 19922944);    //  6,291,456
  unsigned short* linwb = (unsigned short*)(ws + 26214400);    //  1,048,576
  unsigned short* h0buf = (unsigned short*)(ws + 27262976);    //  1,048,576
  unsigned short* h1buf = (unsigned short*)(ws + 28311552);    //  1,048,576
  unsigned*       bar   = (unsigned*)(ws + 29360128);          //     16,384
  unsigned short* y0m   = (unsigned short*)(ws + 29376512);    // 134,217,728
  unsigned short* y1l   = (unsigned short*)(ws + 163594240);   // 134,217,728

  float* out_mean = (float*)d_out;
  float* out_var  = out_mean + SBO_;
  float* preds    = out_mean + 2 * (size_t)SBO_;
  float* hid_out  = out_mean + 2 * (size_t)SBO_ + (size_t)G_ * SBO_;

  unsigned* bar0 = bar;
  unsigned* bar1 = bar + G_ * 64;

  hipMemsetAsync(bar, 0, 16384, stream);

  k_cvt<<<512, 256, 0, stream>>>(input, xb, SB_ * I_);
  k_cvt<<<512, 256, 0, stream>>>(w_ih0, wih0b, 4 * H3_ * I_);
  k_cvt<<<512, 256, 0, stream>>>(w_hh0, whh0b, 4 * H3_ * H_);
  k_cvt<<<512, 256, 0, stream>>>(w_ih1, wih1b, 4 * H3_ * H_);
  k_cvt<<<512, 256, 0, stream>>>(w_hh1, whh1b, 4 * H3_ * H_);
  k_cvt<<<512, 256, 0, stream>>>(lin_w, linwb, 4 * O_ * H_);

  k_gru0<<<512, 128, 0, stream>>>(hidden, xb, wih0b, whh0b, b_ih0, b_hh0, mask,
                                  y0m, h0buf, hid_out, bar0);
  k_gru1<<<512, 128, 0, stream>>>(hidden, y0m, wih1b, whh1b, b_ih1, b_hh1,
                                  y1l, h1buf, hid_out, bar1);
  k_preds<<<8192, 256, 0, stream>>>(y1l, linwb, lin_b, preds);
  k_meanvar<<<8192, 256, 0, stream>>>(preds, out_mean, out_var, SBO_);
}

// Round 4
// 5412.317 us; speedup vs baseline: 2.4289x; 2.4289x over previous
//
#include <hip/hip_runtime.h>

// Problem dims
#define S_ 256
#define B_ 32
#define I_ 256
#define H_ 512
#define H3_ 1536
#define O_ 256
#define G_ 16          // M*P
#define SB_ 8192       // S*B
#define SBO_ 2097152   // S*B*O
#define NSL 32         // col-slices per group (16 cols each)
#define SPIN_CAP (1u << 20)

typedef __attribute__((ext_vector_type(8))) short bf16x8;
typedef __attribute__((ext_vector_type(4))) float f32x4;

#define MFMA16(a, b, c) __builtin_amdgcn_mfma_f32_16x16x32_bf16((a), (b), (c), 0, 0, 0)

static __device__ __forceinline__ unsigned short f2bf(float f) {
  union { float f; unsigned u; } x; x.f = f;
  unsigned u = x.u + 0x7fffu + ((x.u >> 16) & 1u);   // RNE, finite inputs
  return (unsigned short)(u >> 16);
}
static __device__ __forceinline__ float sigmoidf_(float x) {
  return 1.f / (1.f + __expf(-x));
}

// ---- coherent (agent-scope, L1/L2-bypassing) h exchange: NO fences needed ----
static __device__ __forceinline__ bf16x8 ld_hx8(const unsigned short* p) {
  union { unsigned long long q[2]; bf16x8 v; } u;
  u.q[0] = __hip_atomic_load((const unsigned long long*)p,
                             __ATOMIC_RELAXED, __HIP_MEMORY_SCOPE_AGENT);
  u.q[1] = __hip_atomic_load((const unsigned long long*)(p + 4),
                             __ATOMIC_RELAXED, __HIP_MEMORY_SCOPE_AGENT);
  return u.v;
}
static __device__ __forceinline__ void st_h(unsigned short* p, unsigned short v) {
  __hip_atomic_store(p, v, __ATOMIC_RELAXED, __HIP_MEMORY_SCOPE_AGENT);
}

// Arrive: __syncthreads() drains vmcnt (compiler emits full waitcnt before
// s_barrier), so the write-through h stores are at the L3 coherence point
// before thread 0's counter add becomes visible there.
static __device__ __forceinline__ void arrive(unsigned* cnt) {
  __syncthreads();
  if (threadIdx.x == 0)
    __hip_atomic_fetch_add(cnt, 1u, __ATOMIC_RELAXED, __HIP_MEMORY_SCOPE_AGENT);
}
static __device__ __forceinline__ void waitge(unsigned* cnt, unsigned target) {
  if (threadIdx.x == 0) {
    unsigned it = 0;
    while (__hip_atomic_load(cnt, __ATOMIC_RELAXED, __HIP_MEMORY_SCOPE_AGENT) < target) {
      __builtin_amdgcn_s_sleep(2);
      if (++it > SPIN_CAP) break;        // degrade to wrong-numbers, never hang
    }
  }
  __syncthreads();                       // no acquire fence: h reads are sc1 loads
}

// ---------------- f32 -> bf16 convert ----------------
__global__ void k_cvt(const float* __restrict__ src, unsigned short* __restrict__ dst, int n) {
  int i = blockIdx.x * blockDim.x + threadIdx.x;
  int st = gridDim.x * blockDim.x;
  for (; i < n; i += st) dst[i] = f2bf(src[i]);
}

// Swizzled LDS read of a bf16x8 B-fragment; row size = 1<<shift bytes.
static __device__ __forceinline__ bf16x8 lds_b(const char* lds, int lr, int kk, int shift) {
  return *(const bf16x8*)(lds + (((lr << shift) + kk * 2) ^ ((lr & 7) << 4)));
}

// blockIdx -> (group, slice) so a group's 32 blocks share an XCD under the
// "XCD = blockIdx % 8" dispatch heuristic (perf-only; correctness is agent-scope).
#define GRP_OF(blk) ((((blk) & 7) << 1) | ((blk) >> 8))
#define CSL_OF(blk) (((blk) >> 3) & 31)

// ---------------- layer 0: persistent recurrence, fused x@w_ih0^T ----------------
// 512 blocks x 128 thr (2 waves). Block = (group, 16-col slice). LDS 72KB -> 2 blk/CU.
__global__ __launch_bounds__(128) void k_gru0(
    const float* __restrict__ hidden,
    const unsigned short* __restrict__ xb,
    const unsigned short* __restrict__ wih0b,
    const unsigned short* __restrict__ whh0b,
    const float* __restrict__ b_ih0,
    const float* __restrict__ b_hh0,
    const float* __restrict__ mask,
    unsigned short* __restrict__ y0m,
    unsigned short* __restrict__ hbuf,
    float* __restrict__ hid_out,
    unsigned* __restrict__ bar) {
  __shared__ char lds[73728];            // whh slice 48KB @0, wih slice 24KB @49152
  const int blk = blockIdx.x;
  const int grp = GRP_OF(blk), csl = CSL_OF(blk);
  const int colBase = csl * 16;
  const int m = grp >> 2;
  const int tid = threadIdx.x;
  const int w = tid >> 6, l = tid & 63;
  const int la = l & 15, lb = l >> 4;

  // stage whh0 slice: 48 rows (gate*16 + c) x 512 bf16, 1KB rows, XOR-swizzled
  for (int idx = tid; idx < 48 * 64; idx += 128) {
    int lr = idx >> 6, kc = (idx & 63) << 3;
    int gt = lr >> 4, c = lr & 15;
    bf16x8 v = *(const bf16x8*)(whh0b + ((size_t)m * H3_ + gt * H_ + colBase + c) * H_ + kc);
    *(bf16x8*)(lds + ((lr * 1024 + kc * 2) ^ ((lr & 7) << 4))) = v;
  }
  // stage wih0 slice: 48 rows x 256 bf16, 512B rows, XOR-swizzled
  char* ldsi = lds + 49152;
  for (int idx = tid; idx < 48 * 32; idx += 128) {
    int lr = idx >> 5, kc = (idx & 31) << 3;
    int gt = lr >> 4, c = lr & 15;
    bf16x8 v = *(const bf16x8*)(wih0b + ((size_t)m * H3_ + gt * H_ + colBase + c) * I_ + kc);
    *(bf16x8*)(ldsi + ((lr * 512 + kc * 2) ^ ((lr & 7) << 4))) = v;
  }

  const int jh = colBase + la;           // this lane's h column
  const int b0 = w * 16 + lb * 4;        // first of 4 batch rows (D-frag rows)
  float hown[4];
#pragma unroll
  for (int r = 0; r < 4; ++r) {
    float h0 = hidden[((size_t)(grp * 2 + 0) * B_ + b0 + r) * H_ + jh];
    hown[r] = h0;
    st_h(hbuf + ((size_t)(grp * 2 + 0) * B_ + b0 + r) * H_ + jh, f2bf(h0));
  }
  const float bir = b_ih0[m * H3_ + jh];
  const float biz = b_ih0[m * H3_ + H_ + jh];
  const float bin = b_ih0[m * H3_ + 2 * H_ + jh];
  const float bhr = b_hh0[m * H3_ + jh];
  const float bhz = b_hh0[m * H3_ + H_ + jh];
  const float bhn = b_hh0[m * H3_ + 2 * H_ + jh];
  const int lrr = la, lrz = 16 + la, lrn = 32 + la;

  unsigned* cnt = bar + grp * 64;
  arrive(cnt);                           // h0 write-through complete -> count

  for (int s = 0; s < S_; ++s) {
    // ---- barrier-independent part first: ih GEMM + mask prefetch ----
    const unsigned short* xrow = xb + ((size_t)s * B_ + w * 16 + la) * I_;
    f32x4 iR = {}, iZ = {}, iN = {};
#pragma unroll
    for (int kt = 0; kt < 8; ++kt) {     // K=256 ih chains (cached, warm L1/L2)
      int kk = kt * 32 + lb * 8;
      bf16x8 ax = *(const bf16x8*)(xrow + kk);
      iR = MFMA16(ax, lds_b(ldsi, lrr, kk, 9), iR);
      iZ = MFMA16(ax, lds_b(ldsi, lrz, kk, 9), iZ);
      iN = MFMA16(ax, lds_b(ldsi, lrn, kk, 9), iN);
    }
    float mk[4];
#pragma unroll
    for (int r = 0; r < 4; ++r)
      mk[r] = __builtin_nontemporal_load(
          mask + (((size_t)grp * S_ + s) * B_ + b0 + r) * H_ + jh);

    waitge(cnt, (unsigned)NSL * (s + 1));   // h[s] visible at L3

    const unsigned short* hsrc = hbuf + (size_t)(grp * 2 + (s & 1)) * B_ * H_;
    unsigned short* hdst = hbuf + (size_t)(grp * 2 + ((s & 1) ^ 1)) * B_ * H_;
    const unsigned short* hrow = hsrc + (size_t)(w * 16 + la) * H_;
    f32x4 hR = {}, hZ = {}, hN = {};
#pragma unroll
    for (int kt = 0; kt < 16; ++kt) {    // K=512 hh chains (sc1 coherent loads)
      int kk = kt * 32 + lb * 8;
      bf16x8 ah = ld_hx8(hrow + kk);
      hR = MFMA16(ah, lds_b(lds, lrr, kk, 10), hR);
      hZ = MFMA16(ah, lds_b(lds, lrz, kk, 10), hZ);
      hN = MFMA16(ah, lds_b(lds, lrn, kk, 10), hN);
    }
#pragma unroll
    for (int r = 0; r < 4; ++r) {
      int b = b0 + r;
      float rr = sigmoidf_(iR[r] + bir + hR[r] + bhr);
      float zz = sigmoidf_(iZ[r] + biz + hZ[r] + bhz);
      float nn = tanhf(iN[r] + bin + rr * (hN[r] + bhn));
      float hn = (1.f - zz) * nn + zz * hown[r];
      hown[r] = hn;
      st_h(hdst + (size_t)b * H_ + jh, f2bf(hn));
      __builtin_nontemporal_store(f2bf(hn * mk[r]),
          y0m + (((size_t)grp * S_ + s) * B_ + b) * H_ + jh);
    }
    arrive(cnt);
  }
#pragma unroll
  for (int r = 0; r < 4; ++r)
    hid_out[((size_t)(grp * 2 + 0) * B_ + b0 + r) * H_ + jh] = hown[r];
}

// ---------------- layer 1: persistent recurrence, fused y0@w_ih1^T ----------------
// w_ih1 B-frags stream from L1/L2 (same 48KB slice every step, stays warm). LDS 48KB.
__global__ __launch_bounds__(128) void k_gru1(
    const float* __restrict__ hidden,
    const unsigned short* __restrict__ y0m,
    const unsigned short* __restrict__ wih1b,
    const unsigned short* __restrict__ whh1b,
    const float* __restrict__ b_ih1,
    const float* __restrict__ b_hh1,
    unsigned short* __restrict__ y1l,
    unsigned short* __restrict__ hbuf,
    float* __restrict__ hid_out,
    unsigned* __restrict__ bar) {
  __shared__ char lds[49152];
  const int blk = blockIdx.x;
  const int grp = GRP_OF(blk), csl = CSL_OF(blk);
  const int colBase = csl * 16;
  const int m = grp >> 2;
  const int tid = threadIdx.x;
  const int w = tid >> 6, l = tid & 63;
  const int la = l & 15, lb = l >> 4;

  for (int idx = tid; idx < 48 * 64; idx += 128) {
    int lr = idx >> 6, kc = (idx & 63) << 3;
    int gt = lr >> 4, c = lr & 15;
    bf16x8 v = *(const bf16x8*)(whh1b + ((size_t)m * H3_ + gt * H_ + colBase + c) * H_ + kc);
    *(bf16x8*)(lds + ((lr * 1024 + kc * 2) ^ ((lr & 7) << 4))) = v;
  }

  const int jh = colBase + la;
  const int b0 = w * 16 + lb * 4;
  float hown[4];
#pragma unroll
  for (int r = 0; r < 4; ++r) {
    float h0 = hidden[((size_t)(grp * 2 + 1) * B_ + b0 + r) * H_ + jh];
    hown[r] = h0;
    st_h(hbuf + ((size_t)(grp * 2 + 0) * B_ + b0 + r) * H_ + jh, f2bf(h0));
  }
  const float bir = b_ih1[m * H3_ + jh];
  const float biz = b_ih1[m * H3_ + H_ + jh];
  const float bin = b_ih1[m * H3_ + 2 * H_ + jh];
  const float bhr = b_hh1[m * H3_ + jh];
  const float bhz = b_hh1[m * H3_ + H_ + jh];
  const float bhn = b_hh1[m * H3_ + 2 * H_ + jh];
  const unsigned short* wr = wih1b + ((size_t)m * H3_ + jh) * H_;
  const unsigned short* wz = wih1b + ((size_t)m * H3_ + H_ + jh) * H_;
  const unsigned short* wn = wih1b + ((size_t)m * H3_ + 2 * H_ + jh) * H_;
  const int lrr = la, lrz = 16 + la, lrn = 32 + la;

  unsigned* cnt = bar + grp * 64;
  arrive(cnt);

  for (int s = 0; s < S_; ++s) {
    // ---- barrier-independent part first: y0@w_ih1 (y0m written by prev kernel) ----
    const unsigned short* yrow = y0m + (((size_t)grp * S_ + s) * B_ + w * 16 + la) * H_;
    f32x4 iR = {}, iZ = {}, iN = {};
#pragma unroll
    for (int kt = 0; kt < 16; ++kt) {
      int kk = kt * 32 + lb * 8;
      bf16x8 ay = *(const bf16x8*)(yrow + kk);
      iR = MFMA16(ay, *(const bf16x8*)(wr + kk), iR);
      iZ = MFMA16(ay, *(const bf16x8*)(wz + kk), iZ);
      iN = MFMA16(ay, *(const bf16x8*)(wn + kk), iN);
    }

    waitge(cnt, (unsigned)NSL * (s + 1));

    const unsigned short* hsrc = hbuf + (size_t)(grp * 2 + (s & 1)) * B_ * H_;
    unsigned short* hdst = hbuf + (size_t)(grp * 2 + ((s & 1) ^ 1)) * B_ * H_;
    const unsigned short* hrow = hsrc + (size_t)(w * 16 + la) * H_;
    f32x4 hR = {}, hZ = {}, hN = {};
#pragma unroll
    for (int kt = 0; kt < 16; ++kt) {
      int kk = kt * 32 + lb * 8;
      bf16x8 ah = ld_hx8(hrow + kk);
      hR = MFMA16(ah, lds_b(lds, lrr, kk, 10), hR);
      hZ = MFMA16(ah, lds_b(lds, lrz, kk, 10), hZ);
      hN = MFMA16(ah, lds_b(lds, lrn, kk, 10), hN);
    }
#pragma unroll
    for (int r = 0; r < 4; ++r) {
      int b = b0 + r;
      float rr = sigmoidf_(iR[r] + bir + hR[r] + bhr);
      float zz = sigmoidf_(iZ[r] + biz + hZ[r] + bhz);
      float nn = tanhf(iN[r] + bin + rr * (hN[r] + bhn));
      float hn = (1.f - zz) * nn + zz * hown[r];
      hown[r] = hn;
      st_h(hdst + (size_t)b * H_ + jh, f2bf(hn));
      float a = hn >= 0.f ? hn : 0.01f * hn;         // LeakyReLU pre-store
      __builtin_nontemporal_store(f2bf(a),
          y1l + (((size_t)grp * S_ + s) * B_ + b) * H_ + jh);
    }
    arrive(cnt);
  }
#pragma unroll
  for (int r = 0; r < 4; ++r)
    hid_out[((size_t)(grp * 2 + 1) * B_ + b0 + r) * H_ + jh] = hown[r];
}

// ---------------- preds = lrelu(y1) @ lin_w^T + lin_b ----------------
// grid: G * (SB/64) * (O/64) = 16*128*4 = 8192 blocks, 256 thr, 64x64 tiles
__global__ __launch_bounds__(256) void k_preds(const unsigned short* __restrict__ y1l,
                                               const unsigned short* __restrict__ linwb,
                                               const float* __restrict__ lin_b,
                                               float* __restrict__ preds) {
  int bid = blockIdx.x;
  int grp = bid >> 9;
  int rm = bid & 511;
  int rt = rm >> 2, ct = rm & 3;
  int m = grp >> 2;
  int w = threadIdx.x >> 6, l = threadIdx.x & 63;
  int la = l & 15, lb = l >> 4;
  int rowBase = rt * 64 + (w & 1) * 32;
  int colBase = ct * 64 + (w >> 1) * 32;
  f32x4 acc[2][2] = {};
  for (int kt = 0; kt < 16; ++kt) {
    int k = kt * 32 + lb * 8;
    bf16x8 a0 = *(const bf16x8*)(y1l + ((size_t)grp * SB_ + rowBase + la) * H_ + k);
    bf16x8 a1 = *(const bf16x8*)(y1l + ((size_t)grp * SB_ + rowBase + 16 + la) * H_ + k);
    bf16x8 bb0 = *(const bf16x8*)(linwb + ((size_t)m * O_ + colBase + la) * H_ + k);
    bf16x8 bb1 = *(const bf16x8*)(linwb + ((size_t)m * O_ + colBase + 16 + la) * H_ + k);
    acc[0][0] = MFMA16(a0, bb0, acc[0][0]);
    acc[0][1] = MFMA16(a0, bb1, acc[0][1]);
    acc[1][0] = MFMA16(a1, bb0, acc[1][0]);
    acc[1][1] = MFMA16(a1, bb1, acc[1][1]);
  }
  for (int fr = 0; fr < 2; ++fr)
    for (int fc = 0; fc < 2; ++fc)
#pragma unroll
      for (int r = 0; r < 4; ++r) {
        int row = rowBase + fr * 16 + lb * 4 + r;
        int col = colBase + fc * 16 + la;
        preds[((size_t)grp * SB_ + row) * O_ + col] = acc[fr][fc][r] + lin_b[m * O_ + col];
      }
}

// ---------------- mean / unbiased var over the 16 samples ----------------
__global__ __launch_bounds__(256) void k_meanvar(const float* __restrict__ preds,
                                                 float* __restrict__ om,
                                                 float* __restrict__ ov, int n) {
  int i = blockIdx.x * 256 + threadIdx.x;
  if (i >= n) return;
  float v[16], sum = 0.f;
#pragma unroll
  for (int g = 0; g < 16; ++g) { v[g] = preds[(size_t)g * n + i]; sum += v[g]; }
  float mu = sum * 0.0625f;
  float s2 = 0.f;
#pragma unroll
  for (int g = 0; g < 16; ++g) { float d = v[g] - mu; s2 += d * d; }
  om[i] = mu;
  ov[i] = s2 * (1.f / 15.f);
}

extern "C" void kernel_launch(void* const* d_in, const int* in_sizes, int n_in,
                              void* d_out, int out_size, void* d_ws, size_t ws_size,
                              hipStream_t stream) {
  const float* input  = (const float*)d_in[0];
  const float* hidden = (const float*)d_in[1];
  const float* w_ih0  = (const float*)d_in[2];
  const float* w_hh0  = (const float*)d_in[3];
  const float* b_ih0  = (const float*)d_in[4];
  const float* b_hh0  = (const float*)d_in[5];
  const float* w_ih1  = (const float*)d_in[6];
  const float* w_hh1  = (const float*)d_in[7];
  const float* b_ih1  = (const float*)d_in[8];
  const float* b_hh1  = (const float*)d_in[9];
  const float* lin_w  = (const float*)d_in[10];
  const float* lin_b  = (const float*)d_in[11];
  const float* mask   = (const float*)d_in[12];

  // ws layout (bytes), total 297,811,968 (~284 MB)
  char* ws = (char*)d_ws;
  unsigned short* xb    = (unsigned short*)(ws + 0);           //  4,194,304
  unsigned short* wih0b = (unsigned short*)(ws + 4194304);     //  3,145,728
  unsigned short* whh0b = (unsigned short*)(ws + 7340032);     //  6,291,456
  unsigned short* wih1b = (unsigned short*)(ws + 13631488);    //  6,291,456
  unsigned short* whh1b = (unsigned short*)(ws + 19922944);    //  6,291,456
  unsigned short* linwb = (unsigned short*)(ws + 26214400);    //  1,048,576
  unsigned short* h0buf = (unsigned short*)(ws + 27262976);    //  1,048,576
  unsigned short* h1buf = (unsigned short*)(ws + 28311552);    //  1,048,576
  unsigned*       bar   = (unsigned*)(ws + 29360128);          //     16,384
  unsigned short* y0m   = (unsigned short*)(ws + 29376512);    // 134,217,728
  unsigned short* y1l   = (unsigned short*)(ws + 163594240);   // 134,217,728

  float* out_mean = (float*)d_out;
  float* out_var  = out_mean + SBO_;
  float* preds    = out_mean + 2 * (size_t)SBO_;
  float* hid_out  = out_mean + 2 * (size_t)SBO_ + (size_t)G_ * SBO_;

  unsigned* bar0 = bar;
  unsigned* bar1 = bar + G_ * 64;

  hipMemsetAsync(bar, 0, 16384, stream);

  k_cvt<<<512, 256, 0, stream>>>(input, xb, SB_ * I_);
  k_cvt<<<512, 256, 0, stream>>>(w_ih0, wih0b, 4 * H3_ * I_);
  k_cvt<<<512, 256, 0, stream>>>(w_hh0, whh0b, 4 * H3_ * H_);
  k_cvt<<<512, 256, 0, stream>>>(w_ih1, wih1b, 4 * H3_ * H_);
  k_cvt<<<512, 256, 0, stream>>>(w_hh1, whh1b, 4 * H3_ * H_);
  k_cvt<<<512, 256, 0, stream>>>(lin_w, linwb, 4 * O_ * H_);

  k_gru0<<<512, 128, 0, stream>>>(hidden, xb, wih0b, whh0b, b_ih0, b_hh0, mask,
                                  y0m, h0buf, hid_out, bar0);
  k_gru1<<<512, 128, 0, stream>>>(hidden, y0m, wih1b, whh1b, b_ih1, b_hh1,
                                  y1l, h1buf, hid_out, bar1);
  k_preds<<<8192, 256, 0, stream>>>(y1l, linwb, lin_b, preds);
  k_meanvar<<<8192, 256, 0, stream>>>(preds, out_mean, out_var, SBO_);
}

// Round 5
// 4194.168 us; speedup vs baseline: 3.1344x; 1.2904x over previous
//
#include <hip/hip_runtime.h>

// Problem dims
#define S_ 256
#define B_ 32
#define I_ 256
#define H_ 512
#define H3_ 1536
#define O_ 256
#define G_ 16          // M*P
#define SB_ 8192       // S*B
#define SBO_ 2097152   // S*B*O
#define NSL 32         // col-slices per group (16 cols each)
#define SPIN_CAP (1u << 20)

typedef __attribute__((ext_vector_type(8))) short bf16x8;
typedef __attribute__((ext_vector_type(4))) float f32x4;

#define MFMA16(a, b, c) __builtin_amdgcn_mfma_f32_16x16x32_bf16((a), (b), (c), 0, 0, 0)

static __device__ __forceinline__ unsigned short f2bf(float f) {
  union { float f; unsigned u; } x; x.f = f;
  unsigned u = x.u + 0x7fffu + ((x.u >> 16) & 1u);   // RNE, finite inputs
  return (unsigned short)(u >> 16);
}
static __device__ __forceinline__ float sigmoidf_(float x) {
  return 1.f / (1.f + __expf(-x));
}

// ---- coherent (agent-scope, L1/L2-bypassing) h exchange: NO fences needed ----
static __device__ __forceinline__ bf16x8 ld_hx8(const unsigned short* p) {
  union { unsigned long long q[2]; bf16x8 v; } u;
  u.q[0] = __hip_atomic_load((const unsigned long long*)p,
                             __ATOMIC_RELAXED, __HIP_MEMORY_SCOPE_AGENT);
  u.q[1] = __hip_atomic_load((const unsigned long long*)(p + 4),
                             __ATOMIC_RELAXED, __HIP_MEMORY_SCOPE_AGENT);
  return u.v;
}
static __device__ __forceinline__ void st_h(unsigned short* p, unsigned short v) {
  __hip_atomic_store(p, v, __ATOMIC_RELAXED, __HIP_MEMORY_SCOPE_AGENT);
}

// Arrive: __syncthreads() drains each wave's outstanding stores (compiler emits
// vmcnt(0) before s_barrier), so h write-through stores are at the L3 coherence
// point before thread 0's counter add becomes visible there.
static __device__ __forceinline__ void arrive(unsigned* cnt) {
  __syncthreads();
  if (threadIdx.x == 0)
    __hip_atomic_fetch_add(cnt, 1u, __ATOMIC_RELAXED, __HIP_MEMORY_SCOPE_AGENT);
}
static __device__ __forceinline__ void waitge(unsigned* cnt, unsigned target) {
  if (threadIdx.x == 0) {
    unsigned it = 0;
    while (__hip_atomic_load(cnt, __ATOMIC_RELAXED, __HIP_MEMORY_SCOPE_AGENT) < target) {
      __builtin_amdgcn_s_sleep(2);
      if (++it > SPIN_CAP) break;        // degrade to wrong-numbers, never hang
    }
  }
  __syncthreads();                       // no acquire fence: h reads are sc1 loads
}

// ---------------- f32 -> bf16 convert ----------------
__global__ void k_cvt(const float* __restrict__ src, unsigned short* __restrict__ dst, int n) {
  int i = blockIdx.x * blockDim.x + threadIdx.x;
  int st = gridDim.x * blockDim.x;
  for (; i < n; i += st) dst[i] = f2bf(src[i]);
}

// Swizzled LDS read of a bf16x8 B-fragment; row size = 1<<shift bytes.
static __device__ __forceinline__ bf16x8 lds_b(const char* lds, int lr, int kk, int shift) {
  return *(const bf16x8*)(lds + (((lr << shift) + kk * 2) ^ ((lr & 7) << 4)));
}

// blockIdx -> (group, slice) so a group's 32 blocks share an XCD under the
// "XCD = blockIdx % 8" dispatch heuristic (perf-only; correctness is agent-scope).
#define GRP_OF(blk) ((((blk) & 7) << 1) | ((blk) >> 8))
#define CSL_OF(blk) (((blk) >> 3) & 31)

// ---------------- layer 0: persistent recurrence, fused x@w_ih0^T ----------------
// 512 blocks x 256 thr (4 waves): wave w: rt=w&1 (16 batch rows), kh=w>>1 (K half).
// kh0 waves: full ih GEMM + elementwise + stores; kh1 waves: hh K-half + LDS partials.
// LDS: whh0 48K @0, wih0 24K @49152, hh partials 6K @73728 -> 78K, 2 blk/CU.
__global__ __launch_bounds__(256) void k_gru0(
    const float* __restrict__ hidden,
    const unsigned short* __restrict__ xb,
    const unsigned short* __restrict__ wih0b,
    const unsigned short* __restrict__ whh0b,
    const float* __restrict__ b_ih0,
    const float* __restrict__ b_hh0,
    const float* __restrict__ mask,
    unsigned short* __restrict__ y0m,
    unsigned short* __restrict__ hbuf,
    float* __restrict__ hid_out,
    unsigned* __restrict__ bar) {
  __shared__ char lds[79872];
  const int blk = blockIdx.x;
  const int grp = GRP_OF(blk), csl = CSL_OF(blk);
  const int colBase = csl * 16;
  const int m = grp >> 2;
  const int tid = threadIdx.x;
  const int w = tid >> 6, l = tid & 63;
  const int la = l & 15, lb = l >> 4;
  const int rt = w & 1, kh = w >> 1;

  // stage whh0 slice: 48 rows (gate*16+c) x 512 bf16, 1KB rows, XOR-swizzled
  for (int idx = tid; idx < 48 * 64; idx += 256) {
    int lr = idx >> 6, kc = (idx & 63) << 3;
    int gt = lr >> 4, c = lr & 15;
    bf16x8 v = *(const bf16x8*)(whh0b + ((size_t)m * H3_ + gt * H_ + colBase + c) * H_ + kc);
    *(bf16x8*)(lds + ((lr * 1024 + kc * 2) ^ ((lr & 7) << 4))) = v;
  }
  // stage wih0 slice: 48 rows x 256 bf16, 512B rows, XOR-swizzled
  char* ldsi = lds + 49152;
  for (int idx = tid; idx < 48 * 32; idx += 256) {
    int lr = idx >> 5, kc = (idx & 31) << 3;
    int gt = lr >> 4, c = lr & 15;
    bf16x8 v = *(const bf16x8*)(wih0b + ((size_t)m * H3_ + gt * H_ + colBase + c) * I_ + kc);
    *(bf16x8*)(ldsi + ((lr * 512 + kc * 2) ^ ((lr & 7) << 4))) = v;
  }
  char* ldsp = lds + 73728;              // partials: rt*3072 + gate*1024 + l*16

  const int jh = colBase + la;           // this lane's h column
  const int b0 = rt * 16 + lb * 4;       // first of 4 batch rows (D-frag rows)
  float hown[4];
  if (kh == 0) {
#pragma unroll
    for (int r = 0; r < 4; ++r) {
      float h0 = hidden[((size_t)(grp * 2 + 0) * B_ + b0 + r) * H_ + jh];
      hown[r] = h0;
      st_h(hbuf + ((size_t)(grp * 2 + 0) * B_ + b0 + r) * H_ + jh, f2bf(h0));
    }
  }
  const float bir = b_ih0[m * H3_ + jh];
  const float biz = b_ih0[m * H3_ + H_ + jh];
  const float bin = b_ih0[m * H3_ + 2 * H_ + jh];
  const float bhr = b_hh0[m * H3_ + jh];
  const float bhz = b_hh0[m * H3_ + H_ + jh];
  const float bhn = b_hh0[m * H3_ + 2 * H_ + jh];
  const int lrr = la, lrz = 16 + la, lrn = 32 + la;

  unsigned* cnt = bar + grp * 64;
  arrive(cnt);                           // h0 write-through complete -> count

  for (int s = 0; s < S_; ++s) {
    // ---- barrier-independent (kh0): full ih GEMM + mask prefetch ----
    f32x4 iR = {}, iZ = {}, iN = {};
    float mk[4];
    if (kh == 0) {
      const unsigned short* xrow = xb + ((size_t)s * B_ + rt * 16 + la) * I_;
#pragma unroll
      for (int kt = 0; kt < 8; ++kt) {
        int kk = kt * 32 + lb * 8;
        bf16x8 ax = *(const bf16x8*)(xrow + kk);
        iR = MFMA16(ax, lds_b(ldsi, lrr, kk, 9), iR);
        iZ = MFMA16(ax, lds_b(ldsi, lrz, kk, 9), iZ);
        iN = MFMA16(ax, lds_b(ldsi, lrn, kk, 9), iN);
      }
#pragma unroll
      for (int r = 0; r < 4; ++r)
        mk[r] = __builtin_nontemporal_load(
            mask + (((size_t)grp * S_ + s) * B_ + b0 + r) * H_ + jh);
    }

    waitge(cnt, (unsigned)NSL * (s + 1));   // h[s] visible at L3

    const unsigned short* hsrc = hbuf + (size_t)(grp * 2 + (s & 1)) * B_ * H_;
    unsigned short* hdst = hbuf + (size_t)(grp * 2 + ((s & 1) ^ 1)) * B_ * H_;
    const unsigned short* hrow = hsrc + (size_t)(rt * 16 + la) * H_;
    f32x4 hR = {}, hZ = {}, hN = {};
#pragma unroll
    for (int kt = 0; kt < 8; ++kt) {     // this wave's K half of hh
      int kk = kh * 256 + kt * 32 + lb * 8;
      bf16x8 ah = ld_hx8(hrow + kk);
      hR = MFMA16(ah, lds_b(lds, lrr, kk, 10), hR);
      hZ = MFMA16(ah, lds_b(lds, lrz, kk, 10), hZ);
      hN = MFMA16(ah, lds_b(lds, lrn, kk, 10), hN);
    }
    if (kh == 1) {
      *(f32x4*)(ldsp + rt * 3072 + 0 * 1024 + l * 16) = hR;
      *(f32x4*)(ldsp + rt * 3072 + 1 * 1024 + l * 16) = hZ;
      *(f32x4*)(ldsp + rt * 3072 + 2 * 1024 + l * 16) = hN;
    }
    __syncthreads();
    if (kh == 0) {
      hR += *(const f32x4*)(ldsp + rt * 3072 + 0 * 1024 + l * 16);
      hZ += *(const f32x4*)(ldsp + rt * 3072 + 1 * 1024 + l * 16);
      hN += *(const f32x4*)(ldsp + rt * 3072 + 2 * 1024 + l * 16);
#pragma unroll
      for (int r = 0; r < 4; ++r) {
        float rr = sigmoidf_(iR[r] + bir + hR[r] + bhr);
        float zz = sigmoidf_(iZ[r] + biz + hZ[r] + bhz);
        float nn = tanhf(iN[r] + bin + rr * (hN[r] + bhn));
        float hn = (1.f - zz) * nn + zz * hown[r];
        hown[r] = hn;
        st_h(hdst + (size_t)(b0 + r) * H_ + jh, f2bf(hn));
      }
    }
    arrive(cnt);
    if (kh == 0) {                       // y0m stores drain during others' spin
#pragma unroll
      for (int r = 0; r < 4; ++r)
        __builtin_nontemporal_store(f2bf(hown[r] * mk[r]),
            y0m + (((size_t)grp * S_ + s) * B_ + b0 + r) * H_ + jh);
    }
  }
  if (kh == 0) {
#pragma unroll
    for (int r = 0; r < 4; ++r)
      hid_out[((size_t)(grp * 2 + 0) * B_ + b0 + r) * H_ + jh] = hown[r];
  }
}

// ---------------- layer 1: persistent recurrence, fused y0@w_ih1^T ----------------
// Both ih and hh split by K half across wave pairs; wih1 streams from L2 (halved
// per-wave). LDS: whh1 48K + partials 12K = 60K, 2 blk/CU.
__global__ __launch_bounds__(256) void k_gru1(
    const float* __restrict__ hidden,
    const unsigned short* __restrict__ y0m,
    const unsigned short* __restrict__ wih1b,
    const unsigned short* __restrict__ whh1b,
    const float* __restrict__ b_ih1,
    const float* __restrict__ b_hh1,
    unsigned short* __restrict__ y1l,
    unsigned short* __restrict__ hbuf,
    float* __restrict__ hid_out,
    unsigned* __restrict__ bar) {
  __shared__ char lds[61440];
  const int blk = blockIdx.x;
  const int grp = GRP_OF(blk), csl = CSL_OF(blk);
  const int colBase = csl * 16;
  const int m = grp >> 2;
  const int tid = threadIdx.x;
  const int w = tid >> 6, l = tid & 63;
  const int la = l & 15, lb = l >> 4;
  const int rt = w & 1, kh = w >> 1;

  for (int idx = tid; idx < 48 * 64; idx += 256) {
    int lr = idx >> 6, kc = (idx & 63) << 3;
    int gt = lr >> 4, c = lr & 15;
    bf16x8 v = *(const bf16x8*)(whh1b + ((size_t)m * H3_ + gt * H_ + colBase + c) * H_ + kc);
    *(bf16x8*)(lds + ((lr * 1024 + kc * 2) ^ ((lr & 7) << 4))) = v;
  }
  char* ldsp = lds + 49152;              // partials: rt*6144 + v*1024 + l*16

  const int jh = colBase + la;
  const int b0 = rt * 16 + lb * 4;
  float hown[4];
  if (kh == 0) {
#pragma unroll
    for (int r = 0; r < 4; ++r) {
      float h0 = hidden[((size_t)(grp * 2 + 1) * B_ + b0 + r) * H_ + jh];
      hown[r] = h0;
      st_h(hbuf + ((size_t)(grp * 2 + 0) * B_ + b0 + r) * H_ + jh, f2bf(h0));
    }
  }
  const float bir = b_ih1[m * H3_ + jh];
  const float biz = b_ih1[m * H3_ + H_ + jh];
  const float bin = b_ih1[m * H3_ + 2 * H_ + jh];
  const float bhr = b_hh1[m * H3_ + jh];
  const float bhz = b_hh1[m * H3_ + H_ + jh];
  const float bhn = b_hh1[m * H3_ + 2 * H_ + jh];
  const unsigned short* wr = wih1b + ((size_t)m * H3_ + jh) * H_;
  const unsigned short* wz = wih1b + ((size_t)m * H3_ + H_ + jh) * H_;
  const unsigned short* wn = wih1b + ((size_t)m * H3_ + 2 * H_ + jh) * H_;
  const int lrr = la, lrz = 16 + la, lrn = 32 + la;

  unsigned* cnt = bar + grp * 64;
  arrive(cnt);

  for (int s = 0; s < S_; ++s) {
    // ---- barrier-independent: this wave's K half of ih (y0m from prev kernel) ----
    const unsigned short* yrow = y0m + (((size_t)grp * S_ + s) * B_ + rt * 16 + la) * H_;
    f32x4 iR = {}, iZ = {}, iN = {};
#pragma unroll
    for (int kt = 0; kt < 8; ++kt) {
      int kk = kh * 256 + kt * 32 + lb * 8;
      bf16x8 ay = *(const bf16x8*)(yrow + kk);
      iR = MFMA16(ay, *(const bf16x8*)(wr + kk), iR);
      iZ = MFMA16(ay, *(const bf16x8*)(wz + kk), iZ);
      iN = MFMA16(ay, *(const bf16x8*)(wn + kk), iN);
    }

    waitge(cnt, (unsigned)NSL * (s + 1));

    const unsigned short* hsrc = hbuf + (size_t)(grp * 2 + (s & 1)) * B_ * H_;
    unsigned short* hdst = hbuf + (size_t)(grp * 2 + ((s & 1) ^ 1)) * B_ * H_;
    const unsigned short* hrow = hsrc + (size_t)(rt * 16 + la) * H_;
    f32x4 hR = {}, hZ = {}, hN = {};
#pragma unroll
    for (int kt = 0; kt < 8; ++kt) {
      int kk = kh * 256 + kt * 32 + lb * 8;
      bf16x8 ah = ld_hx8(hrow + kk);
      hR = MFMA16(ah, lds_b(lds, lrr, kk, 10), hR);
      hZ = MFMA16(ah, lds_b(lds, lrz, kk, 10), hZ);
      hN = MFMA16(ah, lds_b(lds, lrn, kk, 10), hN);
    }
    if (kh == 1) {
      *(f32x4*)(ldsp + rt * 6144 + 0 * 1024 + l * 16) = iR;
      *(f32x4*)(ldsp + rt * 6144 + 1 * 1024 + l * 16) = iZ;
      *(f32x4*)(ldsp + rt * 6144 + 2 * 1024 + l * 16) = iN;
      *(f32x4*)(ldsp + rt * 6144 + 3 * 1024 + l * 16) = hR;
      *(f32x4*)(ldsp + rt * 6144 + 4 * 1024 + l * 16) = hZ;
      *(f32x4*)(ldsp + rt * 6144 + 5 * 1024 + l * 16) = hN;
    }
    __syncthreads();
    if (kh == 0) {
      iR += *(const f32x4*)(ldsp + rt * 6144 + 0 * 1024 + l * 16);
      iZ += *(const f32x4*)(ldsp + rt * 6144 + 1 * 1024 + l * 16);
      iN += *(const f32x4*)(ldsp + rt * 6144 + 2 * 1024 + l * 16);
      hR += *(const f32x4*)(ldsp + rt * 6144 + 3 * 1024 + l * 16);
      hZ += *(const f32x4*)(ldsp + rt * 6144 + 4 * 1024 + l * 16);
      hN += *(const f32x4*)(ldsp + rt * 6144 + 5 * 1024 + l * 16);
#pragma unroll
      for (int r = 0; r < 4; ++r) {
        float rr = sigmoidf_(iR[r] + bir + hR[r] + bhr);
        float zz = sigmoidf_(iZ[r] + biz + hZ[r] + bhz);
        float nn = tanhf(iN[r] + bin + rr * (hN[r] + bhn));
        float hn = (1.f - zz) * nn + zz * hown[r];
        hown[r] = hn;
        st_h(hdst + (size_t)(b0 + r) * H_ + jh, f2bf(hn));
      }
    }
    arrive(cnt);
    if (kh == 0) {                       // y1l stores drain during others' spin
#pragma unroll
      for (int r = 0; r < 4; ++r) {
        float hn = hown[r];
        float a = hn >= 0.f ? hn : 0.01f * hn;       // LeakyReLU pre-store
        __builtin_nontemporal_store(f2bf(a),
            y1l + (((size_t)grp * S_ + s) * B_ + b0 + r) * H_ + jh);
      }
    }
  }
  if (kh == 0) {
#pragma unroll
    for (int r = 0; r < 4; ++r)
      hid_out[((size_t)(grp * 2 + 1) * B_ + b0 + r) * H_ + jh] = hown[r];
  }
}

// ---------------- preds = lrelu(y1) @ lin_w^T + lin_b ----------------
// grid: G * (SB/64) * (O/64) = 16*128*4 = 8192 blocks, 256 thr, 64x64 tiles
__global__ __launch_bounds__(256) void k_preds(const unsigned short* __restrict__ y1l,
                                               const unsigned short* __restrict__ linwb,
                                               const float* __restrict__ lin_b,
                                               float* __restrict__ preds) {
  int bid = blockIdx.x;
  int grp = bid >> 9;
  int rm = bid & 511;
  int rt = rm >> 2, ct = rm & 3;
  int m = grp >> 2;
  int w = threadIdx.x >> 6, l = threadIdx.x & 63;
  int la = l & 15, lb = l >> 4;
  int rowBase = rt * 64 + (w & 1) * 32;
  int colBase = ct * 64 + (w >> 1) * 32;
  f32x4 acc[2][2] = {};
  for (int kt = 0; kt < 16; ++kt) {
    int k = kt * 32 + lb * 8;
    bf16x8 a0 = *(const bf16x8*)(y1l + ((size_t)grp * SB_ + rowBase + la) * H_ + k);
    bf16x8 a1 = *(const bf16x8*)(y1l + ((size_t)grp * SB_ + rowBase + 16 + la) * H_ + k);
    bf16x8 bb0 = *(const bf16x8*)(linwb + ((size_t)m * O_ + colBase + la) * H_ + k);
    bf16x8 bb1 = *(const bf16x8*)(linwb + ((size_t)m * O_ + colBase + 16 + la) * H_ + k);
    acc[0][0] = MFMA16(a0, bb0, acc[0][0]);
    acc[0][1] = MFMA16(a0, bb1, acc[0][1]);
    acc[1][0] = MFMA16(a1, bb0, acc[1][0]);
    acc[1][1] = MFMA16(a1, bb1, acc[1][1]);
  }
  for (int fr = 0; fr < 2; ++fr)
    for (int fc = 0; fc < 2; ++fc)
#pragma unroll
      for (int r = 0; r < 4; ++r) {
        int row = rowBase + fr * 16 + lb * 4 + r;
        int col = colBase + fc * 16 + la;
        preds[((size_t)grp * SB_ + row) * O_ + col] = acc[fr][fc][r] + lin_b[m * O_ + col];
      }
}

// ---------------- mean / unbiased var over the 16 samples ----------------
__global__ __launch_bounds__(256) void k_meanvar(const float* __restrict__ preds,
                                                 float* __restrict__ om,
                                                 float* __restrict__ ov, int n) {
  int i = blockIdx.x * 256 + threadIdx.x;
  if (i >= n) return;
  float v[16], sum = 0.f;
#pragma unroll
  for (int g = 0; g < 16; ++g) { v[g] = preds[(size_t)g * n + i]; sum += v[g]; }
  float mu = sum * 0.0625f;
  float s2 = 0.f;
#pragma unroll
  for (int g = 0; g < 16; ++g) { float d = v[g] - mu; s2 += d * d; }
  om[i] = mu;
  ov[i] = s2 * (1.f / 15.f);
}

extern "C" void kernel_launch(void* const* d_in, const int* in_sizes, int n_in,
                              void* d_out, int out_size, void* d_ws, size_t ws_size,
                              hipStream_t stream) {
  const float* input  = (const float*)d_in[0];
  const float* hidden = (const float*)d_in[1];
  const float* w_ih0  = (const float*)d_in[2];
  const float* w_hh0  = (const float*)d_in[3];
  const float* b_ih0  = (const float*)d_in[4];
  const float* b_hh0  = (const float*)d_in[5];
  const float* w_ih1  = (const float*)d_in[6];
  const float* w_hh1  = (const float*)d_in[7];
  const float* b_ih1  = (const float*)d_in[8];
  const float* b_hh1  = (const float*)d_in[9];
  const float* lin_w  = (const float*)d_in[10];
  const float* lin_b  = (const float*)d_in[11];
  const float* mask   = (const float*)d_in[12];

  // ws layout (bytes), total 297,811,968 (~284 MB)
  char* ws = (char*)d_ws;
  unsigned short* xb    = (unsigned short*)(ws + 0);           //  4,194,304
  unsigned short* wih0b = (unsigned short*)(ws + 4194304);     //  3,145,728
  unsigned short* whh0b = (unsigned short*)(ws + 7340032);     //  6,291,456
  unsigned short* wih1b = (unsigned short*)(ws + 13631488);    //  6,291,456
  unsigned short* whh1b = (unsigned short*)(ws + 19922944);    //  6,291,456
  unsigned short* linwb = (unsigned short*)(ws + 26214400);    //  1,048,576
  unsigned short* h0buf = (unsigned short*)(ws + 27262976);    //  1,048,576
  unsigned short* h1buf = (unsigned short*)(ws + 28311552);    //  1,048,576
  unsigned*       bar   = (unsigned*)(ws + 29360128);          //     16,384
  unsigned short* y0m   = (unsigned short*)(ws + 29376512);    // 134,217,728
  unsigned short* y1l   = (unsigned short*)(ws + 163594240);   // 134,217,728

  float* out_mean = (float*)d_out;
  float* out_var  = out_mean + SBO_;
  float* preds    = out_mean + 2 * (size_t)SBO_;
  float* hid_out  = out_mean + 2 * (size_t)SBO_ + (size_t)G_ * SBO_;

  unsigned* bar0 = bar;
  unsigned* bar1 = bar + G_ * 64;

  hipMemsetAsync(bar, 0, 16384, stream);

  k_cvt<<<512, 256, 0, stream>>>(input, xb, SB_ * I_);
  k_cvt<<<512, 256, 0, stream>>>(w_ih0, wih0b, 4 * H3_ * I_);
  k_cvt<<<512, 256, 0, stream>>>(w_hh0, whh0b, 4 * H3_ * H_);
  k_cvt<<<512, 256, 0, stream>>>(w_ih1, wih1b, 4 * H3_ * H_);
  k_cvt<<<512, 256, 0, stream>>>(w_hh1, whh1b, 4 * H3_ * H_);
  k_cvt<<<512, 256, 0, stream>>>(lin_w, linwb, 4 * O_ * H_);

  k_gru0<<<512, 256, 0, stream>>>(hidden, xb, wih0b, whh0b, b_ih0, b_hh0, mask,
                                  y0m, h0buf, hid_out, bar0);
  k_gru1<<<512, 256, 0, stream>>>(hidden, y0m, wih1b, whh1b, b_ih1, b_hh1,
                                  y1l, h1buf, hid_out, bar1);
  k_preds<<<8192, 256, 0, stream>>>(y1l, linwb, lin_b, preds);
  k_meanvar<<<8192, 256, 0, stream>>>(preds, out_mean, out_var, SBO_);
}